// Round 24
// baseline (115.302 us; speedup 1.0000x reference)
//
#include <hip/hip_runtime.h>

// Conv2d 3x3, cin=4, cout=4, pad=1, stride=1 on [4,4096,4096] fp32.
//
// Round-24 = R22 (87.5 us best: 512px x 4rows, depth-2 prefetch, 3 LDS
// buffers = 36864 B -> 4 blocks/CU, hoisted halo s_loads, XCD swizzle,
// nt stores) with ONE change: TRANSPOSED LDS staging. Row element e lives
// at [e&3][e>>2] (4 j-phases x 128), written by 12 width-4 global_load_lds
// per wave per stage (per-lane global source at stride 16B; the 4 j-DMAs
// together touch each cache line once-equivalent, L2 serves re-touches).
// Result: ALL compute reads (4 interior + 2 halo per (ci,row)) are
// stride-4B across lanes = 2 lanes/bank = conflict-FREE (m136), killing
// the measured 6.3M-cycle 8-way halo conflict. Uniform 12 DMAs/wave ->
// clean vmcnt countdown 24/24/12/0, never draining early.

#define IW 4096
#define IH 4096
constexpr long long HWsz = (long long)IH * IW;

typedef float v4f __attribute__((ext_vector_type(4)));

__device__ __forceinline__ void gload_lds4(const float* g, float* l) {
    __builtin_amdgcn_global_load_lds(
        (const __attribute__((address_space(1))) char*)g,
        (__attribute__((address_space(3))) char*)l, 4, 0, 0);
}

// buffer layout: [6 rows][4 j][128] floats (3072 floats = 12288 B).
// row r, elem e  ->  rbuf[(r*4 + (e&3))*128 + (e>>2)]
// stage one ci plane: 48 width-4 DMAs (row 0..5 x j 0..3 x half 0..1);
// wave w owns DMAs 12w..12w+11.
__device__ __forceinline__ void stage(const float* __restrict__ xin, int ci,
                                      float* rbuf, int y0, int X0,
                                      int w, int l) {
    const float* plane = xin + (long long)ci * HWsz;
    #pragma unroll
    for (int k = 0; k < 12; ++k) {
        const int d = 12 * w + k;                // DMA id (wave-uniform)
        const int r = d >> 3;                    // staged row 0..5
        const int j = (d & 7) >> 1;              // elem phase 0..3
        const int h = d & 1;                     // half 0..1
        int yy = y0 - 1 + r;
        int yc = yy < 0 ? 0 : (yy >= IH ? IH - 1 : yy);   // clamp: pad rows
        // lane l: global elem 4*(64h+l)+j -> LDS [r][j][64h+l]
        gload_lds4(plane + (long long)yc * IW + (X0 + 4 * (64 * h + l) + j),
                   rbuf + (r * 4 + j) * 128 + 64 * h);
    }
}

// compute one ci; pair p reads staged rows 2p..2p+3 -> out rows yw,yw+1
__device__ __forceinline__ void compute_ci(float acc[2][4][4],
                                           const float* rbuf,
                                           const float hl[4], const float hr[4],
                                           const float* __restrict__ wt,
                                           int ci, int y0, int p_u,
                                           int txs, int iLt, int iRt) {
    #pragma unroll
    for (int dy = 0; dy < 4; ++dy) {
        const int r  = 2 * p_u + dy;             // staged row (wave-uniform)
        const int yy = y0 - 1 + r;               // global input row (uniform)
        if (yy >= 0 && yy < IH) {                // wave-uniform row skip
            // six stride-4B reads: conflict-free (2 lanes/bank)
            const float a0 = rbuf[(r * 4 + 0) * 128 + txs];
            const float a1 = rbuf[(r * 4 + 1) * 128 + txs];
            const float a2 = rbuf[(r * 4 + 2) * 128 + txs];
            const float a3 = rbuf[(r * 4 + 3) * 128 + txs];
            const float Lr = rbuf[(r * 4 + 3) * 128 + iLt];  // elem 4(txs-1)+3
            const float Rr = rbuf[(r * 4 + 0) * 128 + iRt];  // elem 4(txs+1)
            const float L = (txs == 0)   ? hl[dy] : Lr;
            const float R = (txs == 127) ? hr[dy] : Rr;
            float vv[6] = {L, a0, a1, a2, a3, R};
            #pragma unroll
            for (int rk = 0; rk < 3; ++rk) {
                const int o = dy - rk;           // output row offset (0..1)
                if (o >= 0 && o < 2) {
                    #pragma unroll
                    for (int co = 0; co < 4; ++co) {
                        #pragma unroll
                        for (int kx = 0; kx < 3; ++kx) {
                            const float w = wt[((co * 4 + ci) * 3 + rk) * 3 + kx];
                            #pragma unroll
                            for (int p = 0; p < 4; ++p)
                                acc[o][co][p] = fmaf(w, vv[p + kx], acc[o][co][p]);
                        }
                    }
                }
            }
        }
    }
}

__global__ __launch_bounds__(256) void conv3x3_kernel(
    const float* __restrict__ xin,   // [4][4096][4096]
    const float* __restrict__ wt,    // [4][4][3][3]
    float* __restrict__ out)         // [4][4096][4096]
{
    __shared__ __align__(16) float rows[3][3072];      // 36864 B (<40960)

    // grid 8192 = 1024 row-blocks x 8 x-strips; bijective XCD swizzle
    const int bid = blockIdx.x;
    const int swz = (bid & 7) * 1024 + (bid >> 3);
    const int rowblk = swz >> 3;                  // 0..1023
    const int xs     = swz & 7;                   // 0..7
    const int y0     = rowblk << 2;               // 4 output rows
    const int X0     = xs << 9;                   // 512-px strip
    const int t      = (int)threadIdx.x;
    const int w      = t >> 6, l = t & 63;
    const int txs    = t & 127;                   // px index within pair
    const int p_u    = __builtin_amdgcn_readfirstlane(t >> 7);  // pair 0/1
    const int yw     = y0 + 2 * p_u;              // pair's first output row
    // clamped lane-edge indices (in-range garbage, cndmask'd out)
    const int iLt = (txs == 0)   ? 0 : txs - 1;
    const int iRt = (txs == 127) ? 0 : txs + 1;

    // ---- hoisted halo loads: wave-uniform -> scalar loads, issued up
    //      front so latency hides under the prologue DMA waits ----
    float hl[4][4], hr[4][4];                     // [ci][dy]
    #pragma unroll
    for (int ci = 0; ci < 4; ++ci) {
        const float* plane = xin + (long long)ci * HWsz;
        #pragma unroll
        for (int dy = 0; dy < 4; ++dy) {
            const int yy = yw - 1 + dy;
            const bool vrow = (yy >= 0 && yy < IH);
            const long long rb = (long long)(vrow ? yy : 0) * IW;
            hl[ci][dy] = (vrow && X0 > 0)        ? plane[rb + X0 - 1]   : 0.f;
            hr[ci][dy] = (vrow && X0 + 512 < IW) ? plane[rb + X0 + 512] : 0.f;
        }
    }

    float acc[2][4][4];                           // [orow][cout][px]
    #pragma unroll
    for (int o = 0; o < 2; ++o)
        #pragma unroll
        for (int co = 0; co < 4; ++co)
            #pragma unroll
            for (int p = 0; p < 4; ++p) acc[o][co][p] = 0.f;

    // ---- depth-2 pipeline, 12 DMAs/wave/stage, countdown waits ----
    stage(xin, 0, rows[0], y0, X0, w, l);         // prologue
    stage(xin, 1, rows[1], y0, X0, w, l);

    // ci = 0: issue ci=2, wait ci=0 (24 newest stay in flight)
    stage(xin, 2, rows[2], y0, X0, w, l);
    asm volatile("s_waitcnt vmcnt(24)\n\ts_barrier" ::: "memory");
    compute_ci(acc, rows[0], hl[0], hr[0], wt, 0, y0, p_u, txs, iLt, iRt);
    asm volatile("s_barrier" ::: "memory");       // buf0 readers done
    // ci = 1: issue ci=3 into buf0, wait ci=1
    stage(xin, 3, rows[0], y0, X0, w, l);
    asm volatile("s_waitcnt vmcnt(24)\n\ts_barrier" ::: "memory");
    compute_ci(acc, rows[1], hl[1], hr[1], wt, 1, y0, p_u, txs, iLt, iRt);
    // ci = 2: wait ci=2 (ci=3's 12 DMAs stay in flight)
    asm volatile("s_waitcnt vmcnt(12)\n\ts_barrier" ::: "memory");
    compute_ci(acc, rows[2], hl[2], hr[2], wt, 2, y0, p_u, txs, iLt, iRt);
    // ci = 3: drain
    asm volatile("s_waitcnt vmcnt(0)\n\ts_barrier" ::: "memory");
    compute_ci(acc, rows[0], hl[3], hr[3], wt, 3, y0, p_u, txs, iLt, iRt);

    // ---- store: 2 rows x 4 cout nt dwordx4 ----
    const int x0g = X0 + 4 * txs;
    #pragma unroll
    for (int o = 0; o < 2; ++o) {
        const long long obase = (long long)(yw + o) * IW + x0g;
        #pragma unroll
        for (int co = 0; co < 4; ++co) {
            v4f ov;
            ov.x = acc[o][co][0]; ov.y = acc[o][co][1];
            ov.z = acc[o][co][2]; ov.w = acc[o][co][3];
            __builtin_nontemporal_store(ov,
                reinterpret_cast<v4f*>(out + co * HWsz + obase));
        }
    }
}

extern "C" void kernel_launch(void* const* d_in, const int* in_sizes, int n_in,
                              void* d_out, int out_size, void* d_ws, size_t ws_size,
                              hipStream_t stream) {
    const float* xin = (const float*)d_in[0];
    const float* wt  = (const float*)d_in[1];
    float* out       = (float*)d_out;

    dim3 grid(8192), block(256);
    hipLaunchKernelGGL(conv3x3_kernel, grid, block, 0, stream, xin, wt, out);
}

// Round 25
// 113.080 us; speedup vs baseline: 1.0197x; 1.0197x over previous
//
#include <hip/hip_runtime.h>

// Conv2d 3x3, cin=4, cout=4, pad=1, stride=1 on [4,4096,4096] fp32.
//
// Round-24 = R22 (87.5 us best: 512px x 4rows, depth-2 prefetch, 3 LDS
// buffers = 36864 B -> 4 blocks/CU, hoisted halo s_loads, XCD swizzle,
// nt stores) with ONE change: TRANSPOSED LDS staging. Row element e lives
// at [e&3][e>>2] (4 j-phases x 128), written by 12 width-4 global_load_lds
// per wave per stage (per-lane global source at stride 16B; the 4 j-DMAs
// together touch each cache line once-equivalent, L2 serves re-touches).
// Result: ALL compute reads (4 interior + 2 halo per (ci,row)) are
// stride-4B across lanes = 2 lanes/bank = conflict-FREE (m136), killing
// the measured 6.3M-cycle 8-way halo conflict. Uniform 12 DMAs/wave ->
// clean vmcnt countdown 24/24/12/0, never draining early.

#define IW 4096
#define IH 4096
constexpr long long HWsz = (long long)IH * IW;

typedef float v4f __attribute__((ext_vector_type(4)));

__device__ __forceinline__ void gload_lds4(const float* g, float* l) {
    __builtin_amdgcn_global_load_lds(
        (const __attribute__((address_space(1))) char*)g,
        (__attribute__((address_space(3))) char*)l, 4, 0, 0);
}

// buffer layout: [6 rows][4 j][128] floats (3072 floats = 12288 B).
// row r, elem e  ->  rbuf[(r*4 + (e&3))*128 + (e>>2)]
// stage one ci plane: 48 width-4 DMAs (row 0..5 x j 0..3 x half 0..1);
// wave w owns DMAs 12w..12w+11.
__device__ __forceinline__ void stage(const float* __restrict__ xin, int ci,
                                      float* rbuf, int y0, int X0,
                                      int w, int l) {
    const float* plane = xin + (long long)ci * HWsz;
    #pragma unroll
    for (int k = 0; k < 12; ++k) {
        const int d = 12 * w + k;                // DMA id (wave-uniform)
        const int r = d >> 3;                    // staged row 0..5
        const int j = (d & 7) >> 1;              // elem phase 0..3
        const int h = d & 1;                     // half 0..1
        int yy = y0 - 1 + r;
        int yc = yy < 0 ? 0 : (yy >= IH ? IH - 1 : yy);   // clamp: pad rows
        // lane l: global elem 4*(64h+l)+j -> LDS [r][j][64h+l]
        gload_lds4(plane + (long long)yc * IW + (X0 + 4 * (64 * h + l) + j),
                   rbuf + (r * 4 + j) * 128 + 64 * h);
    }
}

// compute one ci; pair p reads staged rows 2p..2p+3 -> out rows yw,yw+1
__device__ __forceinline__ void compute_ci(float acc[2][4][4],
                                           const float* rbuf,
                                           const float hl[4], const float hr[4],
                                           const float* __restrict__ wt,
                                           int ci, int y0, int p_u,
                                           int txs, int iLt, int iRt) {
    #pragma unroll
    for (int dy = 0; dy < 4; ++dy) {
        const int r  = 2 * p_u + dy;             // staged row (wave-uniform)
        const int yy = y0 - 1 + r;               // global input row (uniform)
        if (yy >= 0 && yy < IH) {                // wave-uniform row skip
            // six stride-4B reads: conflict-free (2 lanes/bank)
            const float a0 = rbuf[(r * 4 + 0) * 128 + txs];
            const float a1 = rbuf[(r * 4 + 1) * 128 + txs];
            const float a2 = rbuf[(r * 4 + 2) * 128 + txs];
            const float a3 = rbuf[(r * 4 + 3) * 128 + txs];
            const float Lr = rbuf[(r * 4 + 3) * 128 + iLt];  // elem 4(txs-1)+3
            const float Rr = rbuf[(r * 4 + 0) * 128 + iRt];  // elem 4(txs+1)
            const float L = (txs == 0)   ? hl[dy] : Lr;
            const float R = (txs == 127) ? hr[dy] : Rr;
            float vv[6] = {L, a0, a1, a2, a3, R};
            #pragma unroll
            for (int rk = 0; rk < 3; ++rk) {
                const int o = dy - rk;           // output row offset (0..1)
                if (o >= 0 && o < 2) {
                    #pragma unroll
                    for (int co = 0; co < 4; ++co) {
                        #pragma unroll
                        for (int kx = 0; kx < 3; ++kx) {
                            const float w = wt[((co * 4 + ci) * 3 + rk) * 3 + kx];
                            #pragma unroll
                            for (int p = 0; p < 4; ++p)
                                acc[o][co][p] = fmaf(w, vv[p + kx], acc[o][co][p]);
                        }
                    }
                }
            }
        }
    }
}

__global__ __launch_bounds__(256) void conv3x3_kernel(
    const float* __restrict__ xin,   // [4][4096][4096]
    const float* __restrict__ wt,    // [4][4][3][3]
    float* __restrict__ out)         // [4][4096][4096]
{
    __shared__ __align__(16) float rows[3][3072];      // 36864 B (<40960)

    // grid 8192 = 1024 row-blocks x 8 x-strips; bijective XCD swizzle
    const int bid = blockIdx.x;
    const int swz = (bid & 7) * 1024 + (bid >> 3);
    const int rowblk = swz >> 3;                  // 0..1023
    const int xs     = swz & 7;                   // 0..7
    const int y0     = rowblk << 2;               // 4 output rows
    const int X0     = xs << 9;                   // 512-px strip
    const int t      = (int)threadIdx.x;
    const int w      = t >> 6, l = t & 63;
    const int txs    = t & 127;                   // px index within pair
    const int p_u    = __builtin_amdgcn_readfirstlane(t >> 7);  // pair 0/1
    const int yw     = y0 + 2 * p_u;              // pair's first output row
    // clamped lane-edge indices (in-range garbage, cndmask'd out)
    const int iLt = (txs == 0)   ? 0 : txs - 1;
    const int iRt = (txs == 127) ? 0 : txs + 1;

    // ---- hoisted halo loads: wave-uniform -> scalar loads, issued up
    //      front so latency hides under the prologue DMA waits ----
    float hl[4][4], hr[4][4];                     // [ci][dy]
    #pragma unroll
    for (int ci = 0; ci < 4; ++ci) {
        const float* plane = xin + (long long)ci * HWsz;
        #pragma unroll
        for (int dy = 0; dy < 4; ++dy) {
            const int yy = yw - 1 + dy;
            const bool vrow = (yy >= 0 && yy < IH);
            const long long rb = (long long)(vrow ? yy : 0) * IW;
            hl[ci][dy] = (vrow && X0 > 0)        ? plane[rb + X0 - 1]   : 0.f;
            hr[ci][dy] = (vrow && X0 + 512 < IW) ? plane[rb + X0 + 512] : 0.f;
        }
    }

    float acc[2][4][4];                           // [orow][cout][px]
    #pragma unroll
    for (int o = 0; o < 2; ++o)
        #pragma unroll
        for (int co = 0; co < 4; ++co)
            #pragma unroll
            for (int p = 0; p < 4; ++p) acc[o][co][p] = 0.f;

    // ---- depth-2 pipeline, 12 DMAs/wave/stage, countdown waits ----
    stage(xin, 0, rows[0], y0, X0, w, l);         // prologue
    stage(xin, 1, rows[1], y0, X0, w, l);

    // ci = 0: issue ci=2, wait ci=0 (24 newest stay in flight)
    stage(xin, 2, rows[2], y0, X0, w, l);
    asm volatile("s_waitcnt vmcnt(24)\n\ts_barrier" ::: "memory");
    compute_ci(acc, rows[0], hl[0], hr[0], wt, 0, y0, p_u, txs, iLt, iRt);
    asm volatile("s_barrier" ::: "memory");       // buf0 readers done
    // ci = 1: issue ci=3 into buf0, wait ci=1
    stage(xin, 3, rows[0], y0, X0, w, l);
    asm volatile("s_waitcnt vmcnt(24)\n\ts_barrier" ::: "memory");
    compute_ci(acc, rows[1], hl[1], hr[1], wt, 1, y0, p_u, txs, iLt, iRt);
    // ci = 2: wait ci=2 (ci=3's 12 DMAs stay in flight)
    asm volatile("s_waitcnt vmcnt(12)\n\ts_barrier" ::: "memory");
    compute_ci(acc, rows[2], hl[2], hr[2], wt, 2, y0, p_u, txs, iLt, iRt);
    // ci = 3: drain
    asm volatile("s_waitcnt vmcnt(0)\n\ts_barrier" ::: "memory");
    compute_ci(acc, rows[0], hl[3], hr[3], wt, 3, y0, p_u, txs, iLt, iRt);

    // ---- store: 2 rows x 4 cout nt dwordx4 ----
    const int x0g = X0 + 4 * txs;
    #pragma unroll
    for (int o = 0; o < 2; ++o) {
        const long long obase = (long long)(yw + o) * IW + x0g;
        #pragma unroll
        for (int co = 0; co < 4; ++co) {
            v4f ov;
            ov.x = acc[o][co][0]; ov.y = acc[o][co][1];
            ov.z = acc[o][co][2]; ov.w = acc[o][co][3];
            __builtin_nontemporal_store(ov,
                reinterpret_cast<v4f*>(out + co * HWsz + obase));
        }
    }
}

extern "C" void kernel_launch(void* const* d_in, const int* in_sizes, int n_in,
                              void* d_out, int out_size, void* d_ws, size_t ws_size,
                              hipStream_t stream) {
    const float* xin = (const float*)d_in[0];
    const float* wt  = (const float*)d_in[1];
    float* out       = (float*)d_out;

    dim3 grid(8192), block(256);
    hipLaunchKernelGGL(conv3x3_kernel, grid, block, 0, stream, xin, wt, out);
}